// Round 1
// baseline (1072.930 us; speedup 1.0000x reference)
//
#include <hip/hip_runtime.h>
#include <hip/hip_bf16.h>
#include <stdint.h>

#define T_STEPS 256
#define BATCH   64
#define IN_DIM  512
#define HID     1024
#define OUT_DIM 256
#define G4      4096
#define SENT    0x7FC07FC0u

__device__ __forceinline__ float bfbits2f(uint32_t b16) {
    return __uint_as_float(b16 << 16);
}
__device__ __forceinline__ uint32_t f2bfbits(float f) {
    uint32_t u = __float_as_uint(f);
    u += 0x7fffu + ((u >> 16) & 1u);   // RNE; inputs are finite, never NaN
    return u >> 16;
}
__device__ __forceinline__ float fast_sigmoid(float x) {
    return 1.f / (1.f + __expf(-x));
}
__device__ __forceinline__ float fast_tanh(float x) {
    return 2.f / (1.f + __expf(-2.f * x)) - 1.f;
}

// ---------------------------------------------------------------- init
__global__ void init_sent(uint32_t* __restrict__ p, int n) {
    int i = blockIdx.x * 256 + threadIdx.x;
    if (i < n) p[i] = SENT;
}

// ---------------------------------------------------------------- GEMM C[M][N] = A[M][K] * B[N][K]^T + bias
// BM=64, BN=64, BK=64, 256 threads, 16 outputs/thread (8 rows x 2 cols)
template<bool ABF16>
__global__ __launch_bounds__(256) void gemm_bt(
    const void* __restrict__ Av, long lda,
    const float* __restrict__ Bw, int ldb,
    const float* __restrict__ bias1, const float* __restrict__ bias2,
    float* __restrict__ C, int ldc, int K)
{
    __shared__ float a_lds[64][68];   // [k][r], row stride 68 floats -> 16B-aligned float4 reads
    __shared__ float w_lds[64][65];   // [k][c], +1 pad -> conflict-free
    const int tid = threadIdx.x;
    const int m0 = blockIdx.y * 64, n0 = blockIdx.x * 64;
    const int kl = tid & 63, grp = tid >> 6;      // staging coords
    const int cc = tid & 31, r0 = (tid >> 5) * 8; // compute coords

    float acc[16];
#pragma unroll
    for (int i = 0; i < 16; ++i) acc[i] = 0.f;

    for (int k0 = 0; k0 < K; k0 += 64) {
        __syncthreads();
#pragma unroll
        for (int i = 0; i < 16; ++i) {
            int r = grp + 4 * i;
            long ai = (long)(m0 + r) * lda + k0 + kl;
            float av = ABF16 ? bfbits2f(((const uint16_t*)Av)[ai])
                             : ((const float*)Av)[ai];
            a_lds[kl][r] = av;
            w_lds[kl][r] = Bw[(long)(n0 + r) * ldb + k0 + kl];
        }
        __syncthreads();
#pragma unroll 16
        for (int k = 0; k < 64; ++k) {
            float4 A0 = *(const float4*)&a_lds[k][r0];
            float4 A1 = *(const float4*)&a_lds[k][r0 + 4];
            float w0 = w_lds[k][cc], w1 = w_lds[k][cc + 32];
            float a[8] = {A0.x, A0.y, A0.z, A0.w, A1.x, A1.y, A1.z, A1.w};
#pragma unroll
            for (int i = 0; i < 8; ++i) {
                acc[i]     += a[i] * w0;
                acc[8 + i] += a[i] * w1;
            }
        }
    }
    float b0 = bias1[n0 + cc]      + (bias2 ? bias2[n0 + cc]      : 0.f);
    float b1 = bias1[n0 + cc + 32] + (bias2 ? bias2[n0 + cc + 32] : 0.f);
#pragma unroll
    for (int i = 0; i < 8; ++i) {
        C[(long)(m0 + r0 + i) * ldc + n0 + cc]      = acc[i]     + b0;
        C[(long)(m0 + r0 + i) * ldc + n0 + cc + 32] = acc[8 + i] + b1;
    }
}

// ---------------------------------------------------------------- LSTM recurrence (batch 63 only)
// 256 blocks x 256 threads. Block g owns hidden units [4g, 4g+4) -> 16 gate rows.
// W_hh slice lives in fp32 VGPRs (64/thread). h exchanged via sentinel-polled
// bf16 dwords in h_all[t][512 dwords]; no barriers/cooperative launch needed.
__global__ __launch_bounds__(256) void lstm_rec(
    const float* __restrict__ W_hh,   // [4096][1024] fp32
    const float* __restrict__ xz,     // [256][4096] fp32 (biases included)
    uint32_t* __restrict__ h_all)     // [256][512] dwords = bf16 pairs
{
    __shared__ float h_lds[HID];
    __shared__ float z_lds[16];

    const int g   = blockIdx.x;
    const int tid = threadIdx.x;
    const int kpart = tid & 15;       // 16 threads per row, 64 k each
    const int row   = tid >> 4;       // 0..15 : gate*4 + unit
    const int gate  = row >> 2, ju = row & 3;
    const int grow  = gate * HID + g * 4 + ju;   // global gate-row / xz column

    // Load W slice into registers, chunk order rotated by kpart so that the
    // runtime-rotated LDS reads pair with compile-time register indices.
    float w[64];
#pragma unroll
    for (int i = 0; i < 16; ++i) {
        int ch = (i + kpart) & 15;
        const float4 wv = *(const float4*)&W_hh[(long)grow * HID + kpart * 64 + ch * 4];
        w[4 * i + 0] = wv.x; w[4 * i + 1] = wv.y;
        w[4 * i + 2] = wv.z; w[4 * i + 3] = wv.w;
    }

    float c_state = 0.f;              // live in threads 0..3 only
    float xz_next = 0.f;
    if (kpart == 0) xz_next = xz[grow];   // prefetch t=0

    for (int t = 0; t < T_STEPS; ++t) {
        // ---- stage h_{t-1} into LDS (fp32)
        if (t == 0) {
            float4 z4 = {0.f, 0.f, 0.f, 0.f};
            *(float4*)&h_lds[4 * tid] = z4;
        } else {
            const uint32_t* hsrc = h_all + (size_t)(t - 1) * 512;
            uint32_t v0, v1;
            do { v0 = __hip_atomic_load(&hsrc[2 * tid],     __ATOMIC_RELAXED, __HIP_MEMORY_SCOPE_AGENT); } while (v0 == SENT);
            do { v1 = __hip_atomic_load(&hsrc[2 * tid + 1], __ATOMIC_RELAXED, __HIP_MEMORY_SCOPE_AGENT); } while (v1 == SENT);
            float4 hv = { bfbits2f(v0 & 0xFFFFu), bfbits2f(v0 >> 16),
                          bfbits2f(v1 & 0xFFFFu), bfbits2f(v1 >> 16) };
            *(float4*)&h_lds[4 * tid] = hv;
        }
        __syncthreads();   // A: h ready (and prev z_lds fully consumed)

        float xz_cur = 0.f;
        if (kpart == 0) {
            xz_cur = xz_next;
            int tn = (t + 1 < T_STEPS) ? t + 1 : t;
            xz_next = xz[(long)tn * G4 + grow];   // prefetch next step
        }

        // ---- 64 MACs from registers x LDS (rotated chunks: 2-way banks, free)
        float a0 = 0.f, a1 = 0.f, a2 = 0.f, a3 = 0.f;
#pragma unroll
        for (int i = 0; i < 16; ++i) {
            int ch = (i + kpart) & 15;
            float4 hv = *(const float4*)&h_lds[kpart * 64 + ch * 4];
            a0 += w[4 * i + 0] * hv.x;
            a1 += w[4 * i + 1] * hv.y;
            a2 += w[4 * i + 2] * hv.z;
            a3 += w[4 * i + 3] * hv.w;
        }
        float sum = (a0 + a1) + (a2 + a3);
        sum += __shfl_xor(sum, 1, 16);
        sum += __shfl_xor(sum, 2, 16);
        sum += __shfl_xor(sum, 4, 16);
        sum += __shfl_xor(sum, 8, 16);
        if (kpart == 0) z_lds[row] = sum + xz_cur;
        __syncthreads();   // B: z ready; h_lds reads done

        // ---- gates + state update + publish (threads 0..3)
        if (tid < 4) {
            float zi = z_lds[tid], zf = z_lds[4 + tid];
            float zg = z_lds[8 + tid], zo = z_lds[12 + tid];
            float ii = fast_sigmoid(zi);
            float ff = fast_sigmoid(zf);
            float gg = fast_tanh(zg);
            float oo = fast_sigmoid(zo);
            c_state = ff * c_state + ii * gg;
            float h = oo * fast_tanh(c_state);
            uint32_t hb = f2bfbits(h);
            uint32_t other = __shfl_xor(hb, 1, 64);
            if ((tid & 1) == 0) {
                uint32_t dw = (hb & 0xFFFFu) | (other << 16);
                __hip_atomic_store(&h_all[(size_t)t * 512 + g * 2 + (tid >> 1)], dw,
                                   __ATOMIC_RELAXED, __HIP_MEMORY_SCOPE_AGENT);
            }
        }
    }
}

// ---------------------------------------------------------------- launch
extern "C" void kernel_launch(void* const* d_in, const int* in_sizes, int n_in,
                              void* d_out, int out_size, void* d_ws, size_t ws_size,
                              hipStream_t stream) {
    const float* x    = (const float*)d_in[0];   // [256][64][512]
    const float* W_ih = (const float*)d_in[1];   // [4096][512]
    const float* W_hh = (const float*)d_in[2];   // [4096][1024]
    const float* b_ih = (const float*)d_in[3];   // [4096]
    const float* b_hh = (const float*)d_in[4];   // [4096]
    const float* fc_W = (const float*)d_in[5];   // [256][1024]
    const float* fc_b = (const float*)d_in[6];   // [256]
    float* out = (float*)d_out;                  // [256][256] fp32

    float*    xz    = (float*)d_ws;                                        // 4 MB
    uint32_t* h_all = (uint32_t*)((char*)d_ws + (size_t)T_STEPS * G4 * 4); // 512 KB

    // re-sentinel h_all every replay (graph-captured)
    init_sent<<<(T_STEPS * HID / 2 + 255) / 256, 256, 0, stream>>>(h_all, T_STEPS * HID / 2);

    // xz[t][n] = x[t][63][:] . W_ih[n][:] + b_ih[n] + b_hh[n]
    gemm_bt<false><<<dim3(G4 / 64, T_STEPS / 64), 256, 0, stream>>>(
        (const void*)(x + 63 * IN_DIM), (long)BATCH * IN_DIM,
        W_ih, IN_DIM, b_ih, b_hh, xz, G4, IN_DIM);

    // sequential LSTM over 256 steps, batch 63 only
    lstm_rec<<<256, 256, 0, stream>>>(W_hh, xz, h_all);

    // out[t][o] = h_all[t][:] . fc_W[o][:] + fc_b[o]
    gemm_bt<true><<<dim3(OUT_DIM / 64, T_STEPS / 64), 256, 0, stream>>>(
        (const void*)h_all, HID, fc_W, HID, fc_b, nullptr, out, OUT_DIM, HID);
}